// Round 1
// baseline (114.200 us; speedup 1.0000x reference)
//
#include <hip/hip_runtime.h>

// Problem constants (from reference)
#define BB 256      // batch (both expert and violator)
#define SS 2048     // sequence
#define DD 128      // feature dim
#define MARGIN 10.0f
#define ALPHA 3.0f
#define BETA 0.3f
#define GAMMA 0.3f

// ws layout (floats):
//   [0        .. 65535]  centroids: 512 rows x 128 (expert rows 0..255, violator rows 256..511)
//   [65536    .. 66047]  norms: 512 (||centroid||^2)
//   [66048    .. 66815]  partials: 3 x 256 (sep, ee, vv)
#define WS_CENT    0
#define WS_NORMS   65536
#define WS_PART    66048

// Kernel 1: per (tensor,batch) centroid + squared norm.
// grid.x = 512 (p<256 -> expert batch p, else violator batch p-256), block = 1024.
// Layout: tid = ssub*32 + d4, d4 indexes the 32 float4 chunks of a 128-float row.
// A wave (64 lanes) covers 2 consecutive rows' contiguous 512B chunks -> 1KB coalesced.
__global__ __launch_bounds__(1024) void centroid_kernel(
    const float* __restrict__ E, const float* __restrict__ V,
    float* __restrict__ cent, float* __restrict__ norms)
{
    const int p = blockIdx.x;
    const float* src = (p < BB) ? (E + (size_t)p * SS * DD)
                                : (V + (size_t)(p - BB) * SS * DD);
    const float4* src4 = reinterpret_cast<const float4*>(src);

    const int tid  = threadIdx.x;
    const int d4   = tid & 31;
    const int ssub = tid >> 5;

    float4 acc = make_float4(0.f, 0.f, 0.f, 0.f);
    for (int s = ssub; s < SS; s += 32) {
        float4 x = src4[s * 32 + d4];
        acc.x += x.x; acc.y += x.y; acc.z += x.z; acc.w += x.w;
    }

    __shared__ float4 red[1024];
    red[tid] = acc;
    __syncthreads();
    for (int h = 16; h >= 1; h >>= 1) {
        if (ssub < h) {
            float4 o = red[tid + h * 32];
            float4 m = red[tid];
            m.x += o.x; m.y += o.y; m.z += o.z; m.w += o.w;
            red[tid] = m;
        }
        __syncthreads();
    }

    __shared__ float nrm[32];
    if (tid < 32) {
        float4 c = red[tid];
        const float inv = 1.0f / (float)SS;
        c.x *= inv; c.y *= inv; c.z *= inv; c.w *= inv;
        reinterpret_cast<float4*>(cent)[p * 32 + tid] = c;
        nrm[tid] = c.x * c.x + c.y * c.y + c.z * c.z + c.w * c.w;
    }
    __syncthreads();
    if (tid == 0) {
        float n = 0.f;
        #pragma unroll
        for (int q = 0; q < 32; ++q) n += nrm[q];
        norms[p] = n;
    }
}

// Kernel 2: block i computes
//   sep_partial[i] = sum_j clamp(MARGIN - dist(e_i, v_j), 0)^2
//   ee_partial[i]  = sum_{j>i} sqdist(e_i, e_j)
//   vv_partial[i]  = sum_{j>i} sqdist(v_i, v_j)
// Thread j owns index j. Centroids are L2-resident (256 KB total).
__global__ __launch_bounds__(256) void loss_kernel(
    const float* __restrict__ cent, const float* __restrict__ norms,
    float* __restrict__ partials)
{
    const int i = blockIdx.x;
    const int j = threadIdx.x;
    const float4* C4 = reinterpret_cast<const float4*>(cent);

    __shared__ float4 Ei[32];
    __shared__ float4 Vi[32];
    if (j < 32)       Ei[j]      = C4[i * 32 + j];
    else if (j < 64)  Vi[j - 32] = C4[(BB + i) * 32 + (j - 32)];
    __syncthreads();

    float dev = 0.f, dee = 0.f, dvv = 0.f;
    #pragma unroll 8
    for (int q = 0; q < 32; ++q) {
        const float4 e  = Ei[q];
        const float4 v  = Vi[q];
        const float4 ej = C4[j * 32 + q];
        const float4 vj = C4[(BB + j) * 32 + q];
        dev += e.x * vj.x + e.y * vj.y + e.z * vj.z + e.w * vj.w;
        dee += e.x * ej.x + e.y * ej.y + e.z * ej.z + e.w * ej.w;
        dvv += v.x * vj.x + v.y * vj.y + v.z * vj.z + v.w * vj.w;
    }

    const float ne_i = norms[i];
    const float nv_i = norms[BB + i];
    const float ne_j = norms[j];
    const float nv_j = norms[BB + j];

    // separation term for pair (i, j)
    float sq_ev = fmaxf(ne_i + nv_j - 2.0f * dev, 0.0f);
    float dist  = sqrtf(sq_ev + 1e-12f);
    float t     = fmaxf(MARGIN - dist, 0.0f);
    float sep   = t * t;

    float sq_ee = (j > i) ? fmaxf(ne_i + ne_j - 2.0f * dee, 0.0f) : 0.0f;
    float sq_vv = (j > i) ? fmaxf(nv_i + nv_j - 2.0f * dvv, 0.0f) : 0.0f;

    __shared__ float red[256];
    float sums[3];
    float vals[3] = {sep, sq_ee, sq_vv};
    #pragma unroll
    for (int k = 0; k < 3; ++k) {
        red[j] = vals[k];
        __syncthreads();
        for (int h = 128; h >= 1; h >>= 1) {
            if (j < h) red[j] += red[j + h];
            __syncthreads();
        }
        sums[k] = red[0];
        __syncthreads();
    }

    if (j == 0) {
        partials[i]           = sums[0];
        partials[BB + i]      = sums[1];
        partials[2 * BB + i]  = sums[2];
    }
}

// Kernel 3: final reduction of the 3x256 partials -> scalar loss.
__global__ __launch_bounds__(256) void finalize_kernel(
    const float* __restrict__ partials, float* __restrict__ out)
{
    const int j = threadIdx.x;
    __shared__ float red[256];
    float vals[3] = {partials[j], partials[BB + j], partials[2 * BB + j]};
    float sums[3];
    #pragma unroll
    for (int k = 0; k < 3; ++k) {
        red[j] = vals[k];
        __syncthreads();
        for (int h = 128; h >= 1; h >>= 1) {
            if (j < h) red[j] += red[j + h];
            __syncthreads();
        }
        sums[k] = red[0];
        __syncthreads();
    }
    if (j == 0) {
        const float sep_mean = sums[0] / (float)(BB * BB);          // 65536 pairs
        const float cnt      = (float)(BB * (BB - 1) / 2);           // 32640
        const float ee_mean  = sums[1] / cnt;
        const float vv_mean  = sums[2] / cnt;
        out[0] = ALPHA * sep_mean + BETA * ee_mean + GAMMA * vv_mean;
    }
}

extern "C" void kernel_launch(void* const* d_in, const int* in_sizes, int n_in,
                              void* d_out, int out_size, void* d_ws, size_t ws_size,
                              hipStream_t stream) {
    const float* E = (const float*)d_in[0];
    const float* V = (const float*)d_in[1];
    float* ws   = (float*)d_ws;
    float* cent = ws + WS_CENT;
    float* nrm  = ws + WS_NORMS;
    float* part = ws + WS_PART;
    float* out  = (float*)d_out;

    centroid_kernel<<<512, 1024, 0, stream>>>(E, V, cent, nrm);
    loss_kernel<<<BB, 256, 0, stream>>>(cent, nrm, part);
    finalize_kernel<<<1, 256, 0, stream>>>(part, out);
}

// Round 2
// 98.634 us; speedup vs baseline: 1.1578x; 1.1578x over previous
//
#include <hip/hip_runtime.h>

typedef float f4 __attribute__((ext_vector_type(4)));

// Problem constants (from reference)
#define BB 256      // batch (both expert and violator)
#define SS 2048     // sequence
#define DD 128      // feature dim
#define MARGIN 10.0f
#define ALPHA 3.0f
#define BETA 0.3f
#define GAMMA 0.3f

// ws layout (floats):
//   [0      .. 65535]  centroids: 512 rows x 128 (expert 0..255, violator 256..511)
//   [65536  .. 66047]  norms: 512 (||centroid||^2)
//   [66048  .. 66815]  partials: 3 x 256 (sep, ee, vv)
#define WS_CENT    0
#define WS_NORMS   65536
#define WS_PART    66048

// Kernel 1: per (tensor,batch) centroid + squared norm.
// grid = 512, block = 1024 (16 waves). tid = ssub*32 + d4.
// A wave covers 1 KB contiguous (two 512B row-chunks). 4-way unrolled with
// independent accumulators for MLP; nontemporal loads (data read exactly once).
__global__ __launch_bounds__(1024) void centroid_kernel(
    const float* __restrict__ E, const float* __restrict__ V,
    float* __restrict__ cent, float* __restrict__ norms)
{
    const int p = blockIdx.x;
    const float* src = (p < BB) ? (E + (size_t)p * SS * DD)
                                : (V + (size_t)(p - BB) * SS * DD);
    const f4* src4 = reinterpret_cast<const f4*>(src);

    const int tid  = threadIdx.x;
    const int d4   = tid & 31;   // float4 column 0..31
    const int ssub = tid >> 5;   // row slice 0..31

    const f4* p4 = src4 + (size_t)ssub * 32 + d4;
    f4 a0 = 0.f, a1 = 0.f, a2 = 0.f, a3 = 0.f;
    // s = ssub + 32*k, k = 0..63 ; unroll 4 -> 16 outer iterations
    #pragma unroll 2
    for (int it = 0; it < 16; ++it) {
        f4 x0 = __builtin_nontemporal_load(p4);
        f4 x1 = __builtin_nontemporal_load(p4 + 1024);
        f4 x2 = __builtin_nontemporal_load(p4 + 2048);
        f4 x3 = __builtin_nontemporal_load(p4 + 3072);
        a0 += x0; a1 += x1; a2 += x2; a3 += x3;
        p4 += 4096;
    }
    f4 acc = (a0 + a1) + (a2 + a3);

    // Intra-wave: lanes l and l+32 share d4 with adjacent ssub -> combine.
    acc.x += __shfl_down(acc.x, 32);
    acc.y += __shfl_down(acc.y, 32);
    acc.z += __shfl_down(acc.z, 32);
    acc.w += __shfl_down(acc.w, 32);

    __shared__ f4 red[512];      // 16 waves x 32 columns
    const int wave = tid >> 6;
    const int lane = tid & 63;
    if (lane < 32) red[wave * 32 + lane] = acc;
    __syncthreads();
    for (int h = 8; h >= 1; h >>= 1) {
        if (tid < h * 32) red[tid] += red[tid + h * 32];
        __syncthreads();
    }

    __shared__ float nrm[32];
    if (tid < 32) {
        f4 c = red[tid] * (1.0f / (float)SS);
        reinterpret_cast<f4*>(cent)[p * 32 + tid] = c;
        nrm[tid] = c.x * c.x + c.y * c.y + c.z * c.z + c.w * c.w;
    }
    __syncthreads();
    if (tid == 0) {
        float n = 0.f;
        #pragma unroll
        for (int q = 0; q < 32; ++q) n += nrm[q];
        norms[p] = n;
    }
}

// Kernel 2: block i, thread j:
//   sep term for pair (i,j); ee/vv terms for j>i. Fused 3-value shuffle reduce.
__global__ __launch_bounds__(256) void loss_kernel(
    const float* __restrict__ cent, const float* __restrict__ norms,
    float* __restrict__ partials)
{
    const int i = blockIdx.x;
    const int j = threadIdx.x;
    const f4* C4 = reinterpret_cast<const f4*>(cent);

    __shared__ f4 Ei[32];
    __shared__ f4 Vi[32];
    if (j < 32)       Ei[j]      = C4[i * 32 + j];
    else if (j < 64)  Vi[j - 32] = C4[(BB + i) * 32 + (j - 32)];
    __syncthreads();

    float dev = 0.f, dee = 0.f, dvv = 0.f;
    #pragma unroll 8
    for (int q = 0; q < 32; ++q) {
        const f4 e  = Ei[q];
        const f4 v  = Vi[q];
        const f4 ej = C4[j * 32 + q];
        const f4 vj = C4[(BB + j) * 32 + q];
        f4 t0 = e * vj; dev += t0.x + t0.y + t0.z + t0.w;
        f4 t1 = e * ej; dee += t1.x + t1.y + t1.z + t1.w;
        f4 t2 = v * vj; dvv += t2.x + t2.y + t2.z + t2.w;
    }

    const float ne_i = norms[i];
    const float nv_i = norms[BB + i];
    const float ne_j = norms[j];
    const float nv_j = norms[BB + j];

    float sq_ev = fmaxf(ne_i + nv_j - 2.0f * dev, 0.0f);
    float dist  = sqrtf(sq_ev + 1e-12f);
    float t     = fmaxf(MARGIN - dist, 0.0f);
    float sep   = t * t;

    float see = (j > i) ? fmaxf(ne_i + ne_j - 2.0f * dee, 0.0f) : 0.0f;
    float svv = (j > i) ? fmaxf(nv_i + nv_j - 2.0f * dvv, 0.0f) : 0.0f;

    // fused 3-value wave reduction (64 lanes)
    #pragma unroll
    for (int off = 32; off >= 1; off >>= 1) {
        sep += __shfl_down(sep, off);
        see += __shfl_down(see, off);
        svv += __shfl_down(svv, off);
    }
    __shared__ float wred[4][3];
    if ((j & 63) == 0) {
        wred[j >> 6][0] = sep;
        wred[j >> 6][1] = see;
        wred[j >> 6][2] = svv;
    }
    __syncthreads();
    if (j == 0) {
        partials[i]          = wred[0][0] + wred[1][0] + wred[2][0] + wred[3][0];
        partials[BB + i]     = wred[0][1] + wred[1][1] + wred[2][1] + wred[3][1];
        partials[2 * BB + i] = wred[0][2] + wred[1][2] + wred[2][2] + wred[3][2];
    }
}

// Kernel 3: final reduction of the 3x256 partials -> scalar loss.
__global__ __launch_bounds__(256) void finalize_kernel(
    const float* __restrict__ partials, float* __restrict__ out)
{
    const int j = threadIdx.x;
    float s0 = partials[j];
    float s1 = partials[BB + j];
    float s2 = partials[2 * BB + j];
    #pragma unroll
    for (int off = 32; off >= 1; off >>= 1) {
        s0 += __shfl_down(s0, off);
        s1 += __shfl_down(s1, off);
        s2 += __shfl_down(s2, off);
    }
    __shared__ float wred[4][3];
    if ((j & 63) == 0) {
        wred[j >> 6][0] = s0;
        wred[j >> 6][1] = s1;
        wred[j >> 6][2] = s2;
    }
    __syncthreads();
    if (j == 0) {
        float sums0 = wred[0][0] + wred[1][0] + wred[2][0] + wred[3][0];
        float sums1 = wred[0][1] + wred[1][1] + wred[2][1] + wred[3][1];
        float sums2 = wred[0][2] + wred[1][2] + wred[2][2] + wred[3][2];
        const float sep_mean = sums0 / (float)(BB * BB);
        const float cnt      = (float)(BB * (BB - 1) / 2);
        out[0] = ALPHA * sep_mean + (BETA * sums1 + GAMMA * sums2) / cnt;
    }
}

extern "C" void kernel_launch(void* const* d_in, const int* in_sizes, int n_in,
                              void* d_out, int out_size, void* d_ws, size_t ws_size,
                              hipStream_t stream) {
    const float* E = (const float*)d_in[0];
    const float* V = (const float*)d_in[1];
    float* ws   = (float*)d_ws;
    float* cent = ws + WS_CENT;
    float* nrm  = ws + WS_NORMS;
    float* part = ws + WS_PART;
    float* out  = (float*)d_out;

    centroid_kernel<<<512, 1024, 0, stream>>>(E, V, cent, nrm);
    loss_kernel<<<BB, 256, 0, stream>>>(cent, nrm, part);
    finalize_kernel<<<1, 256, 0, stream>>>(part, out);
}